// Round 3
// baseline (1677.332 us; speedup 1.0000x reference)
//
#include <hip/hip_runtime.h>
#include <math.h>

#define PI_F 3.14159265358979323846f
#define KS 258   // padded column count of half-spectrum G (k in [0,256], stride 258)

// ---------------------------------------------------------------- FFT core
__device__ __forceinline__ void fft512(float* re, float* im,
                                       const float* twr, const float* twi, int t) {
#pragma unroll
  for (int s = 0; s < 9; ++s) {
    __syncthreads();
    int h  = 1 << s;
    int j  = t & (h - 1);
    int i1 = ((t >> s) << (s + 1)) + j;
    int i2 = i1 + h;
    int ti = j << (8 - s);
    float wr = twr[ti], wi = twi[ti];
    float ur = re[i1], ui = im[i1];
    float vr = re[i2], vi = im[i2];
    float tr = vr * wr - vi * wi;
    float tq = vr * wi + vi * wr;
    re[i1] = ur + tr; im[i1] = ui + tq;
    re[i2] = ur - tr; im[i2] = ui - tq;
  }
}

__device__ __forceinline__ void init_tw(float* twr, float* twi, int t) {
  float s, c;
  sincosf(-2.0f * PI_F * (float)t * (1.0f / 512.0f), &s, &c);
  twr[t] = c; twi[t] = s;
}

// ------------------------------------------------- K1: gray + paired-row FFT (Hermitian pack)
__global__ __launch_bounds__(256) void k_rowfft(const float* __restrict__ x,
                                                float2* __restrict__ G) {
  __shared__ float re[512], im[512], twr[256], twi[256];
  int t = threadIdx.x;
  int q = blockIdx.x;
  int b = blockIdx.y;
  int r0 = 2 * q;
  const float* xb = x + ((size_t)b * 3 * 512 + r0) * 512;
  float a0 = 0.299f * xb[t]           + 0.587f * xb[262144 + t]           + 0.114f * xb[524288 + t];
  float a1 = 0.299f * xb[t + 256]     + 0.587f * xb[262144 + t + 256]     + 0.114f * xb[524288 + t + 256];
  float c0 = 0.299f * xb[512 + t]     + 0.587f * xb[262656 + t]           + 0.114f * xb[524800 + t];
  float c1 = 0.299f * xb[512 + t + 256] + 0.587f * xb[262656 + t + 256]   + 0.114f * xb[524800 + t + 256];
  int rv0 = __brev((unsigned)t) >> 23;
  int rv1 = __brev((unsigned)(t + 256)) >> 23;
  re[rv0] = a0; im[rv0] = c0;
  re[rv1] = a1; im[rv1] = c1;
  init_tw(twr, twi, t);
  fft512(re, im, twr, twi, t);
  __syncthreads();
  float2* G0 = G + ((size_t)b * 512 + r0) * KS;
  float2* G1 = G0 + KS;
  for (int k = t; k <= 256; k += 256) {
    int mk = (512 - k) & 511;
    float zr = re[k], zi = im[k];
    float mr = re[mk], mi = im[mk];
    G0[k] = make_float2(0.5f * (zr + mr), 0.5f * (zi - mi));
    G1[k] = make_float2(0.5f * (zi + mi), 0.5f * (mr - zr));
  }
}

// ------------------------------------------------- K1.5: out-of-place transpose G -> GT
__global__ __launch_bounds__(256) void k_transpose(const float2* __restrict__ G,
                                                   float2* __restrict__ GT) {
  __shared__ float2 ta[32][33];
  int kt = blockIdx.x, rt = blockIdx.y, b = blockIdx.z;
  int tx = threadIdx.x, ty = threadIdx.y;
  int k0 = kt * 32, r0 = rt * 32;
  const float2* Gb = G + (size_t)b * 512 * KS;
  float2* GTb = GT + (size_t)b * KS * 512;
#pragma unroll
  for (int i = 0; i < 32; i += 8) {
    int k = k0 + tx;
    float2 v = make_float2(0.0f, 0.0f);
    if (k < KS) v = Gb[(size_t)(r0 + ty + i) * KS + k];
    ta[ty + i][tx] = v;
  }
  __syncthreads();
#pragma unroll
  for (int i = 0; i < 32; i += 8) {
    int k = k0 + ty + i;
    if (k < KS) GTb[(size_t)k * 512 + r0 + tx] = ta[tx][ty + i];
  }
}

// ------------------------------------------------- K2: column FFT + mag/log1p/fftshift + mirror + stats
__global__ __launch_bounds__(256) void k_colfft(const float2* __restrict__ GT,
                                                float* __restrict__ S,
                                                double* __restrict__ stats) {
  __shared__ float re[512], im[512], twr[256], twi[256];
  int t  = threadIdx.x;
  int kc = blockIdx.x;
  int b  = blockIdx.y;
  const float2* Gc = GT + ((size_t)b * KS + kc) * 512;
  float2 v0 = Gc[t], v1 = Gc[t + 256];
  int rv0 = __brev((unsigned)t) >> 23;
  int rv1 = __brev((unsigned)(t + 256)) >> 23;
  re[rv0] = v0.x; im[rv0] = v0.y;
  re[rv1] = v1.x; im[rv1] = v1.y;
  init_tw(twr, twi, t);
  fft512(re, im, twr, twi, t);
  float m0 = log1pf(sqrtf(re[t] * re[t] + im[t] * im[t]));
  float m1 = log1pf(sqrtf(re[t + 256] * re[t + 256] + im[t + 256] * im[t + 256]));
  int v = (kc + 256) & 511;
  float* Sb = S + (size_t)b * 262144;
  Sb[(size_t)v * 512 + t + 256] = m0;
  Sb[(size_t)v * 512 + t]       = m1;
  bool mir = (kc >= 1) && (kc <= 255);
  if (mir) {
    int vp = 256 - kc;
    Sb[(size_t)vp * 512 + ((256 - t) & 511)] = m0;
    Sb[(size_t)vp * 512 + ((512 - t) & 511)] = m1;
  }
  __syncthreads();
  re[t] = m0 + m1;
  im[t] = m0 * m0 + m1 * m1;
  __syncthreads();
  for (int s = 128; s > 0; s >>= 1) {
    if (t < s) { re[t] += re[t + s]; im[t] += im[t + s]; }
    __syncthreads();
  }
  if (t == 0) {
    double wgt = mir ? 2.0 : 1.0;
    atomicAdd(&stats[2 * b],     wgt * (double)re[0]);
    atomicAdd(&stats[2 * b + 1], wgt * (double)im[0]);
  }
}

__global__ void k_zero_stats(double* stats) {
  stats[threadIdx.x] = 0.0;
}

__global__ void k_stats(const double* __restrict__ stats, float2* __restrict__ muinv) {
  int i = threadIdx.x;  // 64
  double n  = 262144.0;
  double mu = stats[2 * i] / n;
  double va = stats[2 * i + 1] / n - mu * mu;
  if (va < 0.0) va = 0.0;
  double sd = sqrt(va);
  muinv[i] = make_float2((float)mu, (float)(1.0 / (sd + 1e-8)));
}

// ------------------------------------------------- K4: conv1(5x5,s2,p2) + BN + ReLU + maxpool2
// oc processed in chunks of 4 with weights preloaded (uniform -> SGPR bursts).
#define TS1 68
__global__ __launch_bounds__(256) void k_conv1(
    const float* __restrict__ S, const float2* __restrict__ muinv,
    const float* __restrict__ w, const float* __restrict__ cb,
    const float* __restrict__ g, const float* __restrict__ bb,
    const float* __restrict__ bm, const float* __restrict__ bv,
    float* __restrict__ h1) {
  __shared__ float tile[67 * TS1];
  int b = blockIdx.y;
  int by = blockIdx.x >> 3, bx = blockIdx.x & 7;
  int y0 = by * 16, x0 = bx * 16;
  int h0 = 4 * y0 - 2, w0 = 4 * x0 - 2;
  float2 mi = muinv[b];
  const float* Sb = S + (size_t)b * 262144;
  for (int idx = threadIdx.x; idx < 67 * 67; idx += 256) {
    int wl = idx / 67, hl = idx - wl * 67;
    int hh = h0 + hl, ww = w0 + wl;
    float val = 0.0f;
    if (hh >= 0 && hh < 512 && ww >= 0 && ww < 512)
      val = (Sb[(size_t)ww * 512 + hh] - mi.x) * mi.y;
    tile[wl * TS1 + hl] = val;
  }
  __syncthreads();
  int ty = threadIdx.x >> 4, tx = threadIdx.x & 15;
  float in[7][7];
#pragma unroll
  for (int j = 0; j < 7; ++j)
#pragma unroll
    for (int i = 0; i < 7; ++i)
      in[i][j] = tile[(4 * tx + j) * TS1 + 4 * ty + i];
  int Y = y0 + ty, X = x0 + tx;
  for (int occ = 0; occ < 8; ++occ) {
    float w4[4][25];
#pragma unroll
    for (int jo = 0; jo < 4; ++jo)
#pragma unroll
      for (int k = 0; k < 25; ++k)
        w4[jo][k] = w[(occ * 4 + jo) * 25 + k];
#pragma unroll
    for (int jo = 0; jo < 4; ++jo) {
      int oc = occ * 4 + jo;
      float a00 = 0.f, a01 = 0.f, a10 = 0.f, a11 = 0.f;
#pragma unroll
      for (int dy = 0; dy < 5; ++dy)
#pragma unroll
        for (int dx = 0; dx < 5; ++dx) {
          float wv = w4[jo][dy * 5 + dx];
          a00 = fmaf(wv, in[dy][dx], a00);
          a01 = fmaf(wv, in[dy][dx + 2], a01);
          a10 = fmaf(wv, in[dy + 2][dx], a10);
          a11 = fmaf(wv, in[dy + 2][dx + 2], a11);
        }
      float m   = fmaxf(fmaxf(a00, a01), fmaxf(a10, a11));
      float inv = g[oc] / sqrtf(bv[oc] + 1e-5f);
      float sh  = cb[oc] * inv + bb[oc] - bm[oc] * inv;
      h1[(((size_t)b * 32 + oc) * 128 + Y) * 128 + X] = fmaxf(m * inv + sh, 0.0f);
    }
  }
}

// ------------------------------------------------- K5: conv2(3x3,s2,p1,32->64) + BN + ReLU + maxpool2
// Thread = 1 conv row x 2 adjacent conv cols (pool pair in-thread), 32 oc.
// Block tile: conv 16x32 (pooled 8x16), 32 oc. ic staged in chunks of 2.
// Patch layout shifted by +1 col so reads are float4-aligned at 4*px.
#define C2STR 68
__global__ __launch_bounds__(256) void k_conv2(
    const float* __restrict__ h1, const float* __restrict__ w,
    const float* __restrict__ cb, const float* __restrict__ g,
    const float* __restrict__ bb, const float* __restrict__ bm,
    const float* __restrict__ bv, float* __restrict__ h2) {
  __shared__ __attribute__((aligned(16))) float tile[2 * 33 * C2STR];  // 17952 B
  int tid = threadIdx.x;
  int b = blockIdx.z, ocb = blockIdx.y;                 // ocb in {0,1}: 32 oc
  int rt = blockIdx.x >> 1, ct = blockIdx.x & 1;
  int ty0 = rt * 16, tx0 = ct * 32;                     // conv-tile origin
  int py = tid >> 4, px = tid & 15;                     // conv row, col-pair
  int cload = tid & 63, rg = tid >> 6;                  // staging mapping
  float acc[32][2];
#pragma unroll
  for (int q = 0; q < 32; ++q) { acc[q][0] = 0.0f; acc[q][1] = 0.0f; }

  for (int ict = 0; ict < 16; ++ict) {
    __syncthreads();
    // stage 2 input channels: patch rows 0..32 (iy=2*ty0-1+ir), cols 0..64 (ix=2*tx0-1+ip)
#pragma unroll
    for (int ic = 0; ic < 2; ++ic) {
      int icg = ict * 2 + ic;
      const float* hp = h1 + (((size_t)b * 32 + icg) * 128) * 128;
      for (int ir = rg; ir < 33; ir += 4) {
        int iy = 2 * ty0 - 1 + ir;
        for (int ip = cload; ip < 65; ip += 64) {
          int ix = 2 * tx0 - 1 + ip;
          float v = 0.0f;
          if (iy >= 0 && iy < 128 && ix >= 0 && ix < 128)
            v = hp[(size_t)iy * 128 + ix];
          tile[(ic * 33 + ir) * C2STR + ip] = v;
        }
      }
    }
    __syncthreads();
#pragma unroll
    for (int ic = 0; ic < 2; ++ic) {
      int icg = ict * 2 + ic;
      float in[3][5];
#pragma unroll
      for (int i = 0; i < 3; ++i) {
        int base = (ic * 33 + 2 * py + i) * C2STR + 4 * px;
        float4 a = *reinterpret_cast<const float4*>(&tile[base]);
        in[i][0] = a.x; in[i][1] = a.y; in[i][2] = a.z; in[i][3] = a.w;
        in[i][4] = tile[base + 4];
      }
#pragma unroll 8
      for (int q = 0; q < 32; ++q) {
        const float* wp = w + (((size_t)(ocb * 32 + q)) * 32 + icg) * 9;
        float wq[9];
#pragma unroll
        for (int k = 0; k < 9; ++k) wq[k] = wp[k];
#pragma unroll
        for (int dy = 0; dy < 3; ++dy)
#pragma unroll
          for (int dx = 0; dx < 3; ++dx) {
            float wv = wq[dy * 3 + dx];
            acc[q][0] = fmaf(wv, in[dy][dx],     acc[q][0]);
            acc[q][1] = fmaf(wv, in[dy][dx + 2], acc[q][1]);
          }
      }
    }
  }
  // pool: cols in-thread, rows via shfl (tid^16 -> py^1)
  bool writer = ((py & 1) == 0);
  int Yp = (ty0 + py) >> 1;
  int Xp = (tx0 >> 1) + px;
#pragma unroll
  for (int q = 0; q < 32; ++q) {
    float m = fmaxf(acc[q][0], acc[q][1]);
    m = fmaxf(m, __shfl_xor(m, 16));
    if (writer) {
      int oc = ocb * 32 + q;
      float inv = g[oc] / sqrtf(bv[oc] + 1e-5f);
      float sh  = cb[oc] * inv + bb[oc] - bm[oc] * inv;
      h2[(((size_t)b * 64 + oc) * 32 + Yp) * 32 + Xp] = fmaxf(m * inv + sh, 0.0f);
    }
  }
}

// ------------------------------------------------- K6: conv3(3x3,s2,p1,64->128) + BN + ReLU + GAP
#define TS3 34
__global__ __launch_bounds__(256) void k_conv3(
    const float* __restrict__ h2, const float* __restrict__ w,
    const float* __restrict__ cb, const float* __restrict__ g,
    const float* __restrict__ bb, const float* __restrict__ bm,
    const float* __restrict__ bv, float* __restrict__ gap) {
  __shared__ __attribute__((aligned(16))) float tile[8 * 33 * TS3];
  __shared__ float red[256];
  int tid = threadIdx.x;
  int ocg = blockIdx.x, b = blockIdx.y;
  int cy = tid >> 4, cx = tid & 15;
  float acc[8];
#pragma unroll
  for (int q = 0; q < 8; ++q) acc[q] = 0.0f;

  for (int ict = 0; ict < 8; ++ict) {
    __syncthreads();
    for (int idx = tid; idx < 8 * 33 * 33; idx += 256) {
      int ic = idx / 1089;
      int rem = idx - ic * 1089;
      int rr = rem / 33, cc = rem - rr * 33;
      int iy = rr - 1, ix = cc - 1;
      float v = 0.0f;
      int icg = ict * 8 + ic;
      if (iy >= 0 && iy < 32 && ix >= 0 && ix < 32)
        v = h2[(((size_t)b * 64 + icg) * 32 + iy) * 32 + ix];
      tile[(ic * 33 + rr) * TS3 + cc] = v;
    }
    __syncthreads();
    for (int ic = 0; ic < 8; ++ic) {
      int icg = ict * 8 + ic;
      float ws[8][9];
#pragma unroll
      for (int q = 0; q < 8; ++q)
#pragma unroll
        for (int k = 0; k < 9; ++k)
          ws[q][k] = w[((size_t)(ocg * 8 + q) * 64 + icg) * 9 + k];
      float in[3][3];
#pragma unroll
      for (int i = 0; i < 3; ++i) {
        const float2* r2 = reinterpret_cast<const float2*>(&tile[(ic * 33 + 2 * cy + i) * TS3 + 2 * cx]);
        float2 a = r2[0];
        in[i][0] = a.x; in[i][1] = a.y;
        in[i][2] = tile[(ic * 33 + 2 * cy + i) * TS3 + 2 * cx + 2];
      }
#pragma unroll
      for (int q = 0; q < 8; ++q)
#pragma unroll
        for (int i = 0; i < 3; ++i)
#pragma unroll
          for (int j = 0; j < 3; ++j)
            acc[q] = fmaf(ws[q][i * 3 + j], in[i][j], acc[q]);
    }
  }
  for (int q = 0; q < 8; ++q) {
    int oc = ocg * 8 + q;
    float inv = g[oc] / sqrtf(bv[oc] + 1e-5f);
    float sh  = cb[oc] * inv + bb[oc] - bm[oc] * inv;
    float val = fmaxf(acc[q] * inv + sh, 0.0f);
    __syncthreads();
    red[tid] = val;
    __syncthreads();
    for (int s = 128; s > 0; s >>= 1) {
      if (tid < s) red[tid] += red[tid + s];
      __syncthreads();
    }
    if (tid == 0) gap[(size_t)b * 128 + oc] = red[0] * (1.0f / 256.0f);
  }
}

// ------------------------------------------------- K7: FC1+ReLU+FC2+ReLU
__global__ __launch_bounds__(256) void k_fc(
    const float* __restrict__ gap,
    const float* __restrict__ w1, const float* __restrict__ b1,
    const float* __restrict__ w2, const float* __restrict__ b2,
    float* __restrict__ out) {
  __shared__ float gv[128], hv[256];
  int b = blockIdx.x, t = threadIdx.x;
  if (t < 128) gv[t] = gap[(size_t)b * 128 + t];
  __syncthreads();
  float a1 = b1[t];
  const float* wr = w1 + (size_t)t * 128;
  for (int k = 0; k < 128; ++k) a1 = fmaf(wr[k], gv[k], a1);
  hv[t] = fmaxf(a1, 0.0f);
  __syncthreads();
  if (t < 128) {
    float a2 = b2[t];
    const float* wr2 = w2 + (size_t)t * 256;
    for (int k = 0; k < 256; ++k) a2 = fmaf(wr2[k], hv[k], a2);
    out[(size_t)b * 128 + t] = fmaxf(a2, 0.0f);
  }
}

// ================================================================ launch
extern "C" void kernel_launch(void* const* d_in, const int* in_sizes, int n_in,
                              void* d_out, int out_size, void* d_ws, size_t ws_size,
                              hipStream_t stream) {
  (void)in_sizes; (void)n_in; (void)out_size; (void)ws_size;
  const float* x   = (const float*)d_in[0];
  const float* c1w = (const float*)d_in[1];
  const float* c1b = (const float*)d_in[2];
  const float* b1g = (const float*)d_in[3];
  const float* b1b = (const float*)d_in[4];
  const float* b1m = (const float*)d_in[5];
  const float* b1v = (const float*)d_in[6];
  const float* c2w = (const float*)d_in[7];
  const float* c2b = (const float*)d_in[8];
  const float* b2g = (const float*)d_in[9];
  const float* b2b = (const float*)d_in[10];
  const float* b2m = (const float*)d_in[11];
  const float* b2v = (const float*)d_in[12];
  const float* c3w = (const float*)d_in[13];
  const float* c3b = (const float*)d_in[14];
  const float* b3g = (const float*)d_in[15];
  const float* b3b = (const float*)d_in[16];
  const float* b3m = (const float*)d_in[17];
  const float* b3v = (const float*)d_in[18];
  const float* f1w = (const float*)d_in[19];
  const float* f1b = (const float*)d_in[20];
  const float* f2w = (const float*)d_in[21];
  const float* f2b = (const float*)d_in[22];
  float* out = (float*)d_out;

  char* ws = (char*)d_ws;
  float2* G     = (float2*)(ws + 0);
  float2* GT    = (float2*)(ws + 67633152ull);
  float*  S     = (float*) (ws + 135266304ull);
  double* stats = (double*)(ws + 202375168ull);
  float2* muinv = (float2*)(ws + 202376192ull);
  float*  gap   = (float*) (ws + 202376704ull);
  float*  h1    = (float*) (ws + 0);
  float*  h2    = (float*) (ws + 135266304ull);

  k_zero_stats<<<1, 128, 0, stream>>>(stats);
  k_rowfft   <<<dim3(256, 64), 256, 0, stream>>>(x, G);
  k_transpose<<<dim3(9, 16, 64), dim3(32, 8), 0, stream>>>(G, GT);
  k_colfft   <<<dim3(257, 64), 256, 0, stream>>>(GT, S, stats);
  k_stats    <<<1, 64, 0, stream>>>(stats, muinv);
  k_conv1    <<<dim3(64, 64), 256, 0, stream>>>(S, muinv, c1w, c1b, b1g, b1b, b1m, b1v, h1);
  k_conv2    <<<dim3(8, 2, 64), 256, 0, stream>>>(h1, c2w, c2b, b2g, b2b, b2m, b2v, h2);
  k_conv3    <<<dim3(16, 64), 256, 0, stream>>>(h2, c3w, c3b, b3g, b3b, b3m, b3v, gap);
  k_fc       <<<64, 256, 0, stream>>>(gap, f1w, f1b, f2w, f2b, out);
}

// Round 4
// 1137.746 us; speedup vs baseline: 1.4743x; 1.4743x over previous
//
#include <hip/hip_runtime.h>
#include <math.h>

#define PI_F 3.14159265358979323846f
#define KS 258   // padded column count of half-spectrum G (k in [0,256], stride 258)

// ---------------------------------------------------------------- FFT core
__device__ __forceinline__ void fft512(float* re, float* im,
                                       const float* twr, const float* twi, int t) {
#pragma unroll
  for (int s = 0; s < 9; ++s) {
    __syncthreads();
    int h  = 1 << s;
    int j  = t & (h - 1);
    int i1 = ((t >> s) << (s + 1)) + j;
    int i2 = i1 + h;
    int ti = j << (8 - s);
    float wr = twr[ti], wi = twi[ti];
    float ur = re[i1], ui = im[i1];
    float vr = re[i2], vi = im[i2];
    float tr = vr * wr - vi * wi;
    float tq = vr * wi + vi * wr;
    re[i1] = ur + tr; im[i1] = ui + tq;
    re[i2] = ur - tr; im[i2] = ui - tq;
  }
}

__device__ __forceinline__ void init_tw(float* twr, float* twi, int t) {
  float s, c;
  sincosf(-2.0f * PI_F * (float)t * (1.0f / 512.0f), &s, &c);
  twr[t] = c; twi[t] = s;
}

// ------------------------------------------------- K1: gray + paired-row FFT (Hermitian pack)
__global__ __launch_bounds__(256) void k_rowfft(const float* __restrict__ x,
                                                float2* __restrict__ G) {
  __shared__ float re[512], im[512], twr[256], twi[256];
  int t = threadIdx.x;
  int q = blockIdx.x;
  int b = blockIdx.y;
  int r0 = 2 * q;
  const float* xb = x + ((size_t)b * 3 * 512 + r0) * 512;
  float a0 = 0.299f * xb[t]           + 0.587f * xb[262144 + t]           + 0.114f * xb[524288 + t];
  float a1 = 0.299f * xb[t + 256]     + 0.587f * xb[262144 + t + 256]     + 0.114f * xb[524288 + t + 256];
  float c0 = 0.299f * xb[512 + t]     + 0.587f * xb[262656 + t]           + 0.114f * xb[524800 + t];
  float c1 = 0.299f * xb[512 + t + 256] + 0.587f * xb[262656 + t + 256]   + 0.114f * xb[524800 + t + 256];
  int rv0 = __brev((unsigned)t) >> 23;
  int rv1 = __brev((unsigned)(t + 256)) >> 23;
  re[rv0] = a0; im[rv0] = c0;
  re[rv1] = a1; im[rv1] = c1;
  init_tw(twr, twi, t);
  fft512(re, im, twr, twi, t);
  __syncthreads();
  float2* G0 = G + ((size_t)b * 512 + r0) * KS;
  float2* G1 = G0 + KS;
  for (int k = t; k <= 256; k += 256) {
    int mk = (512 - k) & 511;
    float zr = re[k], zi = im[k];
    float mr = re[mk], mi = im[mk];
    G0[k] = make_float2(0.5f * (zr + mr), 0.5f * (zi - mi));
    G1[k] = make_float2(0.5f * (zi + mi), 0.5f * (mr - zr));
  }
}

// ------------------------------------------------- K1.5: out-of-place transpose G -> GT
__global__ __launch_bounds__(256) void k_transpose(const float2* __restrict__ G,
                                                   float2* __restrict__ GT) {
  __shared__ float2 ta[32][33];
  int kt = blockIdx.x, rt = blockIdx.y, b = blockIdx.z;
  int tx = threadIdx.x, ty = threadIdx.y;
  int k0 = kt * 32, r0 = rt * 32;
  const float2* Gb = G + (size_t)b * 512 * KS;
  float2* GTb = GT + (size_t)b * KS * 512;
#pragma unroll
  for (int i = 0; i < 32; i += 8) {
    int k = k0 + tx;
    float2 v = make_float2(0.0f, 0.0f);
    if (k < KS) v = Gb[(size_t)(r0 + ty + i) * KS + k];
    ta[ty + i][tx] = v;
  }
  __syncthreads();
#pragma unroll
  for (int i = 0; i < 32; i += 8) {
    int k = k0 + ty + i;
    if (k < KS) GTb[(size_t)k * 512 + r0 + tx] = ta[tx][ty + i];
  }
}

// ------------------------------------------------- K2: column FFT + mag/log1p/fftshift + mirror + stats
__global__ __launch_bounds__(256) void k_colfft(const float2* __restrict__ GT,
                                                float* __restrict__ S,
                                                double* __restrict__ stats) {
  __shared__ float re[512], im[512], twr[256], twi[256];
  int t  = threadIdx.x;
  int kc = blockIdx.x;
  int b  = blockIdx.y;
  const float2* Gc = GT + ((size_t)b * KS + kc) * 512;
  float2 v0 = Gc[t], v1 = Gc[t + 256];
  int rv0 = __brev((unsigned)t) >> 23;
  int rv1 = __brev((unsigned)(t + 256)) >> 23;
  re[rv0] = v0.x; im[rv0] = v0.y;
  re[rv1] = v1.x; im[rv1] = v1.y;
  init_tw(twr, twi, t);
  fft512(re, im, twr, twi, t);
  float m0 = log1pf(sqrtf(re[t] * re[t] + im[t] * im[t]));
  float m1 = log1pf(sqrtf(re[t + 256] * re[t + 256] + im[t + 256] * im[t + 256]));
  int v = (kc + 256) & 511;
  float* Sb = S + (size_t)b * 262144;
  Sb[(size_t)v * 512 + t + 256] = m0;
  Sb[(size_t)v * 512 + t]       = m1;
  bool mir = (kc >= 1) && (kc <= 255);
  if (mir) {
    int vp = 256 - kc;
    Sb[(size_t)vp * 512 + ((256 - t) & 511)] = m0;
    Sb[(size_t)vp * 512 + ((512 - t) & 511)] = m1;
  }
  __syncthreads();
  re[t] = m0 + m1;
  im[t] = m0 * m0 + m1 * m1;
  __syncthreads();
  for (int s = 128; s > 0; s >>= 1) {
    if (t < s) { re[t] += re[t + s]; im[t] += im[t + s]; }
    __syncthreads();
  }
  if (t == 0) {
    double wgt = mir ? 2.0 : 1.0;
    atomicAdd(&stats[2 * b],     wgt * (double)re[0]);
    atomicAdd(&stats[2 * b + 1], wgt * (double)im[0]);
  }
}

__global__ void k_zero_stats(double* stats) {
  stats[threadIdx.x] = 0.0;
}

__global__ void k_stats(const double* __restrict__ stats, float2* __restrict__ muinv) {
  int i = threadIdx.x;  // 64
  double n  = 262144.0;
  double mu = stats[2 * i] / n;
  double va = stats[2 * i + 1] / n - mu * mu;
  if (va < 0.0) va = 0.0;
  double sd = sqrt(va);
  muinv[i] = make_float2((float)mu, (float)(1.0 / (sd + 1e-8)));
}

// ------------------------------------------------- K4: conv1(5x5,s2,p2) + BN + ReLU + maxpool2
#define TS1 68
__global__ __launch_bounds__(256) void k_conv1(
    const float* __restrict__ S, const float2* __restrict__ muinv,
    const float* __restrict__ w, const float* __restrict__ cb,
    const float* __restrict__ g, const float* __restrict__ bb,
    const float* __restrict__ bm, const float* __restrict__ bv,
    float* __restrict__ h1) {
  __shared__ float tile[67 * TS1];
  int b = blockIdx.y;
  int by = blockIdx.x >> 3, bx = blockIdx.x & 7;
  int y0 = by * 16, x0 = bx * 16;
  int h0 = 4 * y0 - 2, w0 = 4 * x0 - 2;
  float2 mi = muinv[b];
  const float* Sb = S + (size_t)b * 262144;
  for (int idx = threadIdx.x; idx < 67 * 67; idx += 256) {
    int wl = idx / 67, hl = idx - wl * 67;
    int hh = h0 + hl, ww = w0 + wl;
    float val = 0.0f;
    if (hh >= 0 && hh < 512 && ww >= 0 && ww < 512)
      val = (Sb[(size_t)ww * 512 + hh] - mi.x) * mi.y;
    tile[wl * TS1 + hl] = val;
  }
  __syncthreads();
  int ty = threadIdx.x >> 4, tx = threadIdx.x & 15;
  float in[7][7];
#pragma unroll
  for (int j = 0; j < 7; ++j)
#pragma unroll
    for (int i = 0; i < 7; ++i)
      in[i][j] = tile[(4 * tx + j) * TS1 + 4 * ty + i];
  int Y = y0 + ty, X = x0 + tx;
  for (int occ = 0; occ < 8; ++occ) {
    float w4[4][25];
#pragma unroll
    for (int jo = 0; jo < 4; ++jo)
#pragma unroll
      for (int k = 0; k < 25; ++k)
        w4[jo][k] = w[(occ * 4 + jo) * 25 + k];
#pragma unroll
    for (int jo = 0; jo < 4; ++jo) {
      int oc = occ * 4 + jo;
      float a00 = 0.f, a01 = 0.f, a10 = 0.f, a11 = 0.f;
#pragma unroll
      for (int dy = 0; dy < 5; ++dy)
#pragma unroll
        for (int dx = 0; dx < 5; ++dx) {
          float wv = w4[jo][dy * 5 + dx];
          a00 = fmaf(wv, in[dy][dx], a00);
          a01 = fmaf(wv, in[dy][dx + 2], a01);
          a10 = fmaf(wv, in[dy + 2][dx], a10);
          a11 = fmaf(wv, in[dy + 2][dx + 2], a11);
        }
      float m   = fmaxf(fmaxf(a00, a01), fmaxf(a10, a11));
      float inv = g[oc] / sqrtf(bv[oc] + 1e-5f);
      float sh  = cb[oc] * inv + bb[oc] - bm[oc] * inv;
      h1[(((size_t)b * 32 + oc) * 128 + Y) * 128 + X] = fmaxf(m * inv + sh, 0.0f);
    }
  }
}

// ------------------------------------------------- K5: conv2(3x3,s2,p1,32->64) + BN + ReLU + maxpool2
// R1 structure, but 8 oc per wave (32 oc per block, ocb grid=2).
// Thread = 2x2 conv quad (one pooled output); ALL loops statically unrolled;
// weights read inline from uniform pointer (SMEM scalar loads, no copies).
#define TS2 36
__global__ __launch_bounds__(256) void k_conv2(
    const float* __restrict__ h1, const float* __restrict__ w,
    const float* __restrict__ cb, const float* __restrict__ g,
    const float* __restrict__ bb, const float* __restrict__ bm,
    const float* __restrict__ bv, float* __restrict__ h2) {
  __shared__ __attribute__((aligned(16))) float tile[8 * 33 * TS2];  // 38016 B
  int tid = threadIdx.x;
  int b = blockIdx.z, ocb = blockIdx.y;                 // ocb in {0,1}
  int rt = blockIdx.x >> 2, ct = blockIdx.x & 3;
  int ty0 = rt * 16, tx0 = ct * 16;                     // conv-tile origin (16x16 conv)
  int wv = tid >> 6;                                    // wave id -> oc subgroup
  int lane = tid & 63;
  int qy = lane >> 3, qx = lane & 7;                    // 8x8 quads
  int iy0 = 2 * ty0 - 1, ix0 = 2 * tx0 - 1;
  int ocbase = ocb * 32 + wv * 8;
  float acc[8][4];
#pragma unroll
  for (int q = 0; q < 8; ++q)
#pragma unroll
    for (int p = 0; p < 4; ++p) acc[q][p] = 0.0f;

  for (int ict = 0; ict < 4; ++ict) {
    __syncthreads();
    for (int idx = tid; idx < 8 * 33 * 33; idx += 256) {
      int ic = idx / 1089;
      int rem = idx - ic * 1089;
      int rr = rem / 33, cc = rem - rr * 33;
      int iy = iy0 + rr, ix = ix0 + cc;
      float v = 0.0f;
      int icg = ict * 8 + ic;
      if (iy >= 0 && iy < 128 && ix >= 0 && ix < 128)
        v = h1[(((size_t)b * 32 + icg) * 128 + iy) * 128 + ix];
      tile[(ic * 33 + rr) * TS2 + cc] = v;
    }
    __syncthreads();
    int rbase = 4 * qy, cbase = 4 * qx;
#pragma unroll
    for (int ic = 0; ic < 8; ++ic) {
      int icg = ict * 8 + ic;
      float in[5][5];
#pragma unroll
      for (int i = 0; i < 5; ++i) {
        int base = (ic * 33 + rbase + i) * TS2 + cbase;
        float4 a = *reinterpret_cast<const float4*>(&tile[base]);
        in[i][0] = a.x; in[i][1] = a.y; in[i][2] = a.z; in[i][3] = a.w;
        in[i][4] = tile[base + 4];
      }
      const float* wic = w + ((size_t)ocbase * 32 + icg) * 9;
#pragma unroll
      for (int q = 0; q < 8; ++q) {
        const float* wo = wic + (size_t)q * 32 * 9;
#pragma unroll
        for (int dy = 0; dy < 3; ++dy)
#pragma unroll
          for (int dx = 0; dx < 3; ++dx) {
            float wvv = wo[dy * 3 + dx];
            acc[q][0] = fmaf(wvv, in[dy][dx],         acc[q][0]);
            acc[q][1] = fmaf(wvv, in[dy][dx + 2],     acc[q][1]);
            acc[q][2] = fmaf(wvv, in[dy + 2][dx],     acc[q][2]);
            acc[q][3] = fmaf(wvv, in[dy + 2][dx + 2], acc[q][3]);
          }
      }
    }
  }
  int Yp = (ty0 >> 1) + qy, Xp = (tx0 >> 1) + qx;
#pragma unroll
  for (int q = 0; q < 8; ++q) {
    int oc = ocbase + q;
    float m   = fmaxf(fmaxf(acc[q][0], acc[q][1]), fmaxf(acc[q][2], acc[q][3]));
    float inv = g[oc] / sqrtf(bv[oc] + 1e-5f);
    float sh  = cb[oc] * inv + bb[oc] - bm[oc] * inv;
    h2[(((size_t)b * 64 + oc) * 32 + Yp) * 32 + Xp] = fmaxf(m * inv + sh, 0.0f);
  }
}

// ------------------------------------------------- K6: conv3(3x3,s2,p1,64->128) + BN + ReLU + GAP
#define TS3 34
__global__ __launch_bounds__(256) void k_conv3(
    const float* __restrict__ h2, const float* __restrict__ w,
    const float* __restrict__ cb, const float* __restrict__ g,
    const float* __restrict__ bb, const float* __restrict__ bm,
    const float* __restrict__ bv, float* __restrict__ gap) {
  __shared__ __attribute__((aligned(16))) float tile[8 * 33 * TS3];
  __shared__ float red[256];
  int tid = threadIdx.x;
  int ocg = blockIdx.x, b = blockIdx.y;
  int cy = tid >> 4, cx = tid & 15;
  float acc[8];
#pragma unroll
  for (int q = 0; q < 8; ++q) acc[q] = 0.0f;

  for (int ict = 0; ict < 8; ++ict) {
    __syncthreads();
    for (int idx = tid; idx < 8 * 33 * 33; idx += 256) {
      int ic = idx / 1089;
      int rem = idx - ic * 1089;
      int rr = rem / 33, cc = rem - rr * 33;
      int iy = rr - 1, ix = cc - 1;
      float v = 0.0f;
      int icg = ict * 8 + ic;
      if (iy >= 0 && iy < 32 && ix >= 0 && ix < 32)
        v = h2[(((size_t)b * 64 + icg) * 32 + iy) * 32 + ix];
      tile[(ic * 33 + rr) * TS3 + cc] = v;
    }
    __syncthreads();
#pragma unroll
    for (int ic = 0; ic < 8; ++ic) {
      int icg = ict * 8 + ic;
      float in[3][3];
#pragma unroll
      for (int i = 0; i < 3; ++i) {
        const float2* r2 = reinterpret_cast<const float2*>(&tile[(ic * 33 + 2 * cy + i) * TS3 + 2 * cx]);
        float2 a = r2[0];
        in[i][0] = a.x; in[i][1] = a.y;
        in[i][2] = tile[(ic * 33 + 2 * cy + i) * TS3 + 2 * cx + 2];
      }
      const float* wic = w + ((size_t)(ocg * 8) * 64 + icg) * 9;
#pragma unroll
      for (int q = 0; q < 8; ++q) {
        const float* wo = wic + (size_t)q * 64 * 9;
#pragma unroll
        for (int i = 0; i < 3; ++i)
#pragma unroll
          for (int j = 0; j < 3; ++j)
            acc[q] = fmaf(wo[i * 3 + j], in[i][j], acc[q]);
      }
    }
  }
  for (int q = 0; q < 8; ++q) {
    int oc = ocg * 8 + q;
    float inv = g[oc] / sqrtf(bv[oc] + 1e-5f);
    float sh  = cb[oc] * inv + bb[oc] - bm[oc] * inv;
    float val = fmaxf(acc[q] * inv + sh, 0.0f);
    __syncthreads();
    red[tid] = val;
    __syncthreads();
    for (int s = 128; s > 0; s >>= 1) {
      if (tid < s) red[tid] += red[tid + s];
      __syncthreads();
    }
    if (tid == 0) gap[(size_t)b * 128 + oc] = red[0] * (1.0f / 256.0f);
  }
}

// ------------------------------------------------- K7: FC1+ReLU+FC2+ReLU
__global__ __launch_bounds__(256) void k_fc(
    const float* __restrict__ gap,
    const float* __restrict__ w1, const float* __restrict__ b1,
    const float* __restrict__ w2, const float* __restrict__ b2,
    float* __restrict__ out) {
  __shared__ float gv[128], hv[256];
  int b = blockIdx.x, t = threadIdx.x;
  if (t < 128) gv[t] = gap[(size_t)b * 128 + t];
  __syncthreads();
  float a1 = b1[t];
  const float* wr = w1 + (size_t)t * 128;
  for (int k = 0; k < 128; ++k) a1 = fmaf(wr[k], gv[k], a1);
  hv[t] = fmaxf(a1, 0.0f);
  __syncthreads();
  if (t < 128) {
    float a2 = b2[t];
    const float* wr2 = w2 + (size_t)t * 256;
    for (int k = 0; k < 256; ++k) a2 = fmaf(wr2[k], hv[k], a2);
    out[(size_t)b * 128 + t] = fmaxf(a2, 0.0f);
  }
}

// ================================================================ launch
extern "C" void kernel_launch(void* const* d_in, const int* in_sizes, int n_in,
                              void* d_out, int out_size, void* d_ws, size_t ws_size,
                              hipStream_t stream) {
  (void)in_sizes; (void)n_in; (void)out_size; (void)ws_size;
  const float* x   = (const float*)d_in[0];
  const float* c1w = (const float*)d_in[1];
  const float* c1b = (const float*)d_in[2];
  const float* b1g = (const float*)d_in[3];
  const float* b1b = (const float*)d_in[4];
  const float* b1m = (const float*)d_in[5];
  const float* b1v = (const float*)d_in[6];
  const float* c2w = (const float*)d_in[7];
  const float* c2b = (const float*)d_in[8];
  const float* b2g = (const float*)d_in[9];
  const float* b2b = (const float*)d_in[10];
  const float* b2m = (const float*)d_in[11];
  const float* b2v = (const float*)d_in[12];
  const float* c3w = (const float*)d_in[13];
  const float* c3b = (const float*)d_in[14];
  const float* b3g = (const float*)d_in[15];
  const float* b3b = (const float*)d_in[16];
  const float* b3m = (const float*)d_in[17];
  const float* b3v = (const float*)d_in[18];
  const float* f1w = (const float*)d_in[19];
  const float* f1b = (const float*)d_in[20];
  const float* f2w = (const float*)d_in[21];
  const float* f2b = (const float*)d_in[22];
  float* out = (float*)d_out;

  char* ws = (char*)d_ws;
  float2* G     = (float2*)(ws + 0);
  float2* GT    = (float2*)(ws + 67633152ull);
  float*  S     = (float*) (ws + 135266304ull);
  double* stats = (double*)(ws + 202375168ull);
  float2* muinv = (float2*)(ws + 202376192ull);
  float*  gap   = (float*) (ws + 202376704ull);
  float*  h1    = (float*) (ws + 0);
  float*  h2    = (float*) (ws + 135266304ull);

  k_zero_stats<<<1, 128, 0, stream>>>(stats);
  k_rowfft   <<<dim3(256, 64), 256, 0, stream>>>(x, G);
  k_transpose<<<dim3(9, 16, 64), dim3(32, 8), 0, stream>>>(G, GT);
  k_colfft   <<<dim3(257, 64), 256, 0, stream>>>(GT, S, stats);
  k_stats    <<<1, 64, 0, stream>>>(stats, muinv);
  k_conv1    <<<dim3(64, 64), 256, 0, stream>>>(S, muinv, c1w, c1b, b1g, b1b, b1m, b1v, h1);
  k_conv2    <<<dim3(16, 2, 64), 256, 0, stream>>>(h1, c2w, c2b, b2g, b2b, b2m, b2v, h2);
  k_conv3    <<<dim3(16, 64), 256, 0, stream>>>(h2, c3w, c3b, b3g, b3b, b3m, b3v, gap);
  k_fc       <<<64, 256, 0, stream>>>(gap, f1w, f1b, f2w, f2b, out);
}